// Round 3
// baseline (1097.051 us; speedup 1.0000x reference)
//
#include <hip/hip_runtime.h>
#include <hip/hip_bf16.h>

#define D 64
#define MARGIN 4e-5f
#define WPB 4      // waves per block (k-split factor)
#define RPB 64     // rows per block

// ---------------------------------------------------------------------------
// VectorQuantizer. Harness ref is a numpy-float32 recompute; argmin must
// bit-match np-f32: xx pairwise-8 sum, sgemm sequential-k FMA, first-min.
// Screen: proxy dist = ee - 2*dot in high-accuracy fp32 (err ~5e-8).
// np-f32 noise vs proxy <= ~1.6e-5 => proxy gap >= MARGIN decides np argmin.
// Ambiguous rows -> wave-per-row exact np-f32 emulation (vq_fallback).
// Block = 4 waves x 64 rows; wave w scans codes [256w,256w+256); LDS merge.
// d_out (float): quantized[N*D] | loss[1] | indices[N] | perplexity[1]
// ws: counts u32[K] | nunc u32+pad | loss f64 | ee_np f32[K] | list u32[]
// ---------------------------------------------------------------------------

__device__ __forceinline__ float np_pairwise_sumsq64(const float* a) {
    float r[8];
#pragma unroll
    for (int j = 0; j < 8; ++j) r[j] = __fmul_rn(a[j], a[j]);
#pragma unroll
    for (int i = 8; i < 64; i += 8)
#pragma unroll
        for (int j = 0; j < 8; ++j)
            r[j] = __fadd_rn(r[j], __fmul_rn(a[i + j], a[i + j]));
    return __fadd_rn(
        __fadd_rn(__fadd_rn(r[0], r[1]), __fadd_rn(r[2], r[3])),
        __fadd_rn(__fadd_rn(r[4], r[5]), __fadd_rn(r[6], r[7])));
}

__global__ __launch_bounds__(256) void vq_prep(const float* __restrict__ emb, int K,
                                               float* __restrict__ eenp) {
    int k = blockIdx.x * blockDim.x + threadIdx.x;
    if (k >= K) return;
    eenp[k] = np_pairwise_sumsq64(emb + (size_t)k * D);
}

__global__ __launch_bounds__(256, 4) void vq_screen(
    const float* __restrict__ x, const float* __restrict__ emb,
    const float* __restrict__ eenp, int N, int K,
    float* __restrict__ outq, float* __restrict__ outidx,
    unsigned* __restrict__ counts, double* __restrict__ loss,
    unsigned* __restrict__ nunc, unsigned* __restrict__ list, unsigned cap) {
    const int w = threadIdx.x >> 6;
    const int lane = threadIdx.x & 63;
    const int row0 = blockIdx.x * RPB;
    const int r = row0 + lane;

    // this thread's row in registers
    float xr[D];
    {
        const float4* xp = (const float4*)(x + (size_t)r * D);
#pragma unroll
        for (int j = 0; j < D / 4; ++j) {
            float4 v = xp[j];
            xr[4 * j + 0] = v.x; xr[4 * j + 1] = v.y;
            xr[4 * j + 2] = v.z; xr[4 * j + 3] = v.w;
        }
    }

    // scan this wave's code chunk
    float m1 = 1e30f, m2 = 1e30f;
    int bi = 0;
    const int kbase = w * (K / WPB);
    for (int kk = 0; kk < K / WPB; ++kk) {
        const int k = kbase + kk;
        const float4* ep = (const float4*)(emb + (size_t)k * D);  // wave-uniform
        float a0 = 0.f, a1 = 0.f, a2 = 0.f, a3 = 0.f;
#pragma unroll
        for (int j = 0; j < D / 4; ++j) {
            float4 ev = ep[j];
            a0 = fmaf(xr[4 * j + 0], ev.x, a0);
            a1 = fmaf(xr[4 * j + 1], ev.y, a1);
            a2 = fmaf(xr[4 * j + 2], ev.z, a2);
            a3 = fmaf(xr[4 * j + 3], ev.w, a3);
        }
        float dot = (a0 + a1) + (a2 + a3);
        float dist = fmaf(-2.f, dot, eenp[k]);
        if (dist < m1) { m2 = m1; m1 = dist; bi = k; }
        else if (dist < m2) { m2 = dist; }
    }

    // merge the 4 k-partitions per row (group-ascending => np first-min)
    __shared__ float sm1[WPB][RPB], sm2[WPB][RPB];
    __shared__ int sbi[WPB][RPB];
    __shared__ int sdec[RPB];
    sm1[w][lane] = m1; sm2[w][lane] = m2; sbi[w][lane] = bi;
    __syncthreads();

    if (w == 0) {
        float gm1 = sm1[0][lane], gm2 = sm2[0][lane];
        int gbi = sbi[0][lane];
#pragma unroll
        for (int g = 1; g < WPB; ++g) {
            float a = sm1[g][lane], b = sm2[g][lane];
            if (a < gm1) { gm2 = fminf(gm1, b); gbi = sbi[g][lane]; gm1 = a; }
            else { gm2 = fminf(gm2, a); }
        }
        int dec = gbi;
        if (gm2 - gm1 < MARGIN) {
            unsigned pos = atomicAdd(nunc, 1u);
            if (pos < cap) {
                list[pos] = (unsigned)r;
                dec = -1;
            } else {
                // cold overflow: exact np-f32 argmin with direct global reads
                const float* xp0 = x + (size_t)r * D;
                float rr[8];
#pragma unroll
                for (int j = 0; j < 8; ++j) rr[j] = __fmul_rn(xp0[j], xp0[j]);
                for (int i = 8; i < 64; i += 8)
#pragma unroll
                    for (int j = 0; j < 8; ++j)
                        rr[j] = __fadd_rn(rr[j], __fmul_rn(xp0[i + j], xp0[i + j]));
                float xx = __fadd_rn(
                    __fadd_rn(__fadd_rn(rr[0], rr[1]), __fadd_rn(rr[2], rr[3])),
                    __fadd_rn(__fadd_rn(rr[4], rr[5]), __fadd_rn(rr[6], rr[7])));
                float bm = 1e30f;
                int bb = 0;
                for (int k2 = 0; k2 < K; ++k2) {
                    const float* e = emb + (size_t)k2 * D;
                    float dt = 0.f;
                    for (int d = 0; d < D; ++d) dt = __fmaf_rn(xp0[d], e[d], dt);
                    float dist = __fsub_rn(__fadd_rn(xx, eenp[k2]),
                                           __fmul_rn(2.0f, dt));
                    if (dist < bm) { bm = dist; bb = k2; }
                }
                dec = bb;
            }
        }
        if (dec >= 0) {
            outidx[r] = (float)dec;
            atomicAdd(counts + dec, 1u);
        }
        sdec[lane] = dec;
    }
    __syncthreads();

    // cooperative output: 4 threads per row, consecutive 16B => coalesced
    const int l = threadIdx.x >> 2;
    const int q = threadIdx.x & 3;
    double lpart = 0.0;
    const int b = sdec[l];
    if (b >= 0) {
        const float4* ep = (const float4*)(emb + (size_t)b * D + q * 16);
        const float4* xp = (const float4*)(x + (size_t)(row0 + l) * D + q * 16);
        float4* qp = (float4*)(outq + (size_t)(row0 + l) * D + q * 16);
#pragma unroll
        for (int j = 0; j < 4; ++j) {
            float4 ev = ep[j], xv = xp[j];
            qp[j] = ev;
            double d0 = (double)ev.x - (double)xv.x;
            double d1 = (double)ev.y - (double)xv.y;
            double d2 = (double)ev.z - (double)xv.z;
            double d3 = (double)ev.w - (double)xv.w;
            lpart += d0 * d0 + d1 * d1 + d2 * d2 + d3 * d3;
        }
    }
#pragma unroll
    for (int off = 32; off; off >>= 1) lpart += __shfl_down(lpart, off);
    __shared__ double ls[WPB];
    if (lane == 0) ls[w] = lpart;
    __syncthreads();
    if (threadIdx.x == 0) {
        double s = ls[0] + ls[1] + ls[2] + ls[3];
        atomicAdd(loss, s);
    }
}

// wave-per-row exact numpy-f32 argmin for ambiguous rows
__global__ __launch_bounds__(64) void vq_fallback(
    const float* __restrict__ x, const float* __restrict__ emb,
    const float* __restrict__ eenp, int N, int K,
    float* __restrict__ outq, float* __restrict__ outidx,
    unsigned* __restrict__ counts, double* __restrict__ loss,
    const unsigned* __restrict__ nunc, const unsigned* __restrict__ list,
    unsigned cap) {
    unsigned n = *nunc;
    if (n > cap) n = cap;
    int lane = threadIdx.x;
    const int KP = K / 64;  // 16
    __shared__ float sx[D];
    for (unsigned i = blockIdx.x; i < n; i += gridDim.x) {
        int r = (int)list[i];
        sx[lane] = x[(size_t)r * D + lane];
        __syncthreads();
        float xx = np_pairwise_sumsq64(sx);  // broadcast LDS reads, np-exact
        float bm = 1e30f;
        int bi = 0;
#pragma unroll 4
        for (int kk = 0; kk < KP; ++kk) {
            int k = lane * KP + kk;  // ascending within lane
            const float* e = emb + (size_t)k * D;
            float dot = 0.f;
#pragma unroll 8
            for (int d = 0; d < D; ++d) dot = __fmaf_rn(sx[d], e[d], dot);
            float dist = __fsub_rn(__fadd_rn(xx, eenp[k]), __fmul_rn(2.0f, dot));
            if (dist < bm) { bm = dist; bi = k; }
        }
#pragma unroll
        for (int off = 1; off < 64; off <<= 1) {
            float ov = __shfl_xor(bm, off);
            int oi = __shfl_xor(bi, off);
            if (ov < bm || (ov == bm && oi < bi)) { bm = ov; bi = oi; }
        }
        float ev = emb[(size_t)bi * D + lane];
        float xv = sx[lane];
        outq[(size_t)r * D + lane] = ev;
        double df = (double)ev - (double)xv;
        double lp = df * df;
#pragma unroll
        for (int off = 32; off; off >>= 1) lp += __shfl_down(lp, off);
        if (lane == 0) {
            outidx[r] = (float)bi;
            atomicAdd(counts + bi, 1u);
            atomicAdd(loss, lp);
        }
        __syncthreads();
    }
}

__global__ __launch_bounds__(256) void vq_final(
    const unsigned* __restrict__ counts, const double* __restrict__ loss,
    int N, int K, float* __restrict__ out_loss, float* __restrict__ out_perp) {
    double part = 0.0;
    for (int k = threadIdx.x; k < K; k += 256) {
        double p = (double)counts[k] / (double)N;
        part += p * log(p + 1e-10);
    }
#pragma unroll
    for (int off = 32; off; off >>= 1) part += __shfl_down(part, off);
    __shared__ double ls[4];
    if ((threadIdx.x & 63) == 0) ls[threadIdx.x >> 6] = part;
    __syncthreads();
    if (threadIdx.x == 0) {
        double s = ls[0] + ls[1] + ls[2] + ls[3];
        *out_perp = (float)exp(-s);
        double diff2 = *loss / ((double)N * (double)D);
        *out_loss = (float)(1.25 * diff2);
    }
}

extern "C" void kernel_launch(void* const* d_in, const int* in_sizes, int n_in,
                              void* d_out, int out_size, void* d_ws, size_t ws_size,
                              hipStream_t stream) {
    const float* x = (const float*)d_in[0];
    const float* emb = (const float*)d_in[1];
    int N = in_sizes[0] / D;
    int K = in_sizes[1] / D;

    float* outq = (float*)d_out;
    float* out_loss = outq + (size_t)N * D;
    float* outidx = out_loss + 1;
    float* out_perp = outidx + N;

    char* ws = (char*)d_ws;
    unsigned* counts = (unsigned*)ws;                        // K*4
    unsigned* nunc = (unsigned*)(ws + (size_t)K * 4);        // 4 (+4 pad)
    double* loss = (double*)(ws + (size_t)K * 4 + 8);        // 8
    float* eenp = (float*)(ws + (size_t)K * 4 + 16);         // K*4
    size_t head = (size_t)K * 8 + 16;
    unsigned* list = (unsigned*)(ws + head);
    unsigned cap = 0;
    if (ws_size > head + 4) cap = (unsigned)((ws_size - head) / 4);
    if (cap > (unsigned)N) cap = (unsigned)N;

    hipMemsetAsync(d_ws, 0, (size_t)K * 4 + 16, stream);  // counts+nunc+loss

    vq_prep<<<(K + 255) / 256, 256, 0, stream>>>(emb, K, eenp);
    vq_screen<<<N / RPB, 256, 0, stream>>>(x, emb, eenp, N, K,
                                           outq, outidx, counts, loss,
                                           nunc, list, cap);
    vq_fallback<<<2048, 64, 0, stream>>>(x, emb, eenp, N, K, outq, outidx,
                                         counts, loss, nunc, list, cap);
    vq_final<<<1, 256, 0, stream>>>(counts, loss, N, K, out_loss, out_perp);
}

// Round 4
// 225.551 us; speedup vs baseline: 4.8639x; 4.8639x over previous
//
#include <hip/hip_runtime.h>
#include <hip/hip_bf16.h>

#define D 64
#define MARGIN 4e-5f

typedef __attribute__((ext_vector_type(8))) short bf16x8;
typedef __attribute__((ext_vector_type(4))) float f32x4;

// ---------------------------------------------------------------------------
// VectorQuantizer. Harness ref = numpy-f32 recompute; argmin must bit-match
// np-f32 (xx pairwise-8 sum, sequential-k FMA sgemm, first-min). Screen is a
// split-bf16 MFMA proxy (err <= ~3e-7 << MARGIN): dist = ee - 2*dot where
// dot = xh*eh + xh*el + xl*eh via mfma_f32_16x16x32_bf16, acc seeded with
// -ee/2 so argmin(dist) == argmax(acc). Rows with top-2 gap < MARGIN go to
// the np-f32-exact wave-per-row fallback. Ties: group-ascending order +
// strict compares + index tie-break == numpy first-occurrence.
// d_out (float): quantized[N*D] | loss[1] | indices[N] | perplexity[1]
// ws: counts u32[K] | nunc+pad | loss f64 | neh f32[K] | eenp f32[K]
//     | eh bf16[K*D] | el bf16[K*D] | list u32[]
// ---------------------------------------------------------------------------

__device__ __forceinline__ float np_pairwise_sumsq64(const float* a) {
    float r[8];
#pragma unroll
    for (int j = 0; j < 8; ++j) r[j] = __fmul_rn(a[j], a[j]);
#pragma unroll
    for (int i = 8; i < 64; i += 8)
#pragma unroll
        for (int j = 0; j < 8; ++j)
            r[j] = __fadd_rn(r[j], __fmul_rn(a[i + j], a[i + j]));
    return __fadd_rn(
        __fadd_rn(__fadd_rn(r[0], r[1]), __fadd_rn(r[2], r[3])),
        __fadd_rn(__fadd_rn(r[4], r[5]), __fadd_rn(r[6], r[7])));
}

__device__ __forceinline__ unsigned short f32_bf16_rne(float f) {
    unsigned u = __float_as_uint(f);
    return (unsigned short)((u + 0x7fffu + ((u >> 16) & 1u)) >> 16);
}

__global__ __launch_bounds__(256) void vq_prep(const float* __restrict__ emb, int K,
                                               float* __restrict__ eenp,
                                               float* __restrict__ neh,
                                               unsigned short* __restrict__ eh,
                                               unsigned short* __restrict__ el) {
    int k = blockIdx.x * blockDim.x + threadIdx.x;
    if (k >= K) return;
    const float* e = emb + (size_t)k * D;
    float s = np_pairwise_sumsq64(e);
    eenp[k] = s;
    neh[k] = -0.5f * s;
#pragma unroll 8
    for (int d = 0; d < D; ++d) {
        float f = e[d];
        unsigned short hb = f32_bf16_rne(f);
        float hf = __uint_as_float(((unsigned)hb) << 16);
        eh[(size_t)k * D + d] = hb;
        el[(size_t)k * D + d] = f32_bf16_rne(f - hf);
    }
}

// exact numpy-f32 argmin for one row (overflow path, ~never executed)
__device__ int np_exact_argmin(const float* xr, const float* __restrict__ emb,
                               const float* __restrict__ eenp, int K) {
    float xx = np_pairwise_sumsq64(xr);
    float bm = 1e30f;
    int bi = 0;
    for (int k = 0; k < K; ++k) {
        const float* e = emb + (size_t)k * D;
        float dot = 0.f;
#pragma unroll 8
        for (int d = 0; d < D; ++d) dot = __fmaf_rn(xr[d], e[d], dot);
        float dist = __fsub_rn(__fadd_rn(xx, eenp[k]), __fmul_rn(2.0f, dot));
        if (dist < bm) { bm = dist; bi = k; }
    }
    return bi;
}

#define CVT8(F0, F1, H, L)                                                    \
    do {                                                                      \
        float _f[8] = {F0.x, F0.y, F0.z, F0.w, F1.x, F1.y, F1.z, F1.w};       \
        _Pragma("unroll") for (int _i = 0; _i < 8; ++_i) {                    \
            unsigned _u = __float_as_uint(_f[_i]);                            \
            unsigned _hb = (_u + 0x7fffu + ((_u >> 16) & 1u)) >> 16;          \
            float _hf = __uint_as_float(_hb << 16);                           \
            float _r = _f[_i] - _hf;                                          \
            unsigned _u2 = __float_as_uint(_r);                               \
            unsigned _lb = (_u2 + 0x7fffu + ((_u2 >> 16) & 1u)) >> 16;        \
            H[_i] = (short)_hb;                                               \
            L[_i] = (short)_lb;                                               \
        }                                                                     \
    } while (0)

#define LOADA(A0, A1, A2, A3, B, T)                                           \
    do {                                                                      \
        const unsigned short* _pe = eh + (((size_t)((T) + sub)) << 6) + (grp << 3); \
        const unsigned short* _pl = el + (((size_t)((T) + sub)) << 6) + (grp << 3); \
        A0 = *(const bf16x8*)_pe;  A1 = *(const bf16x8*)(_pe + 32);           \
        A2 = *(const bf16x8*)_pl;  A3 = *(const bf16x8*)(_pl + 32);           \
        B = *(const f32x4*)(neh + (T) + (grp << 2));                          \
    } while (0)

__global__ __launch_bounds__(256) void vq_screen(
    const float* __restrict__ x, const float* __restrict__ emb,
    const unsigned short* __restrict__ eh, const unsigned short* __restrict__ el,
    const float* __restrict__ neh, const float* __restrict__ eenp,
    int N, int Kc,
    float* __restrict__ outq, float* __restrict__ outidx,
    unsigned* __restrict__ counts, double* __restrict__ loss,
    unsigned* __restrict__ nunc, unsigned* __restrict__ list, unsigned cap) {
    const int lane = threadIdx.x & 63;
    const int row0 = blockIdx.x * 256 + (threadIdx.x >> 6) * 64;  // 64 rows/wave
    const int sub = lane & 15, grp = lane >> 4;

    // persistent B frags: x rows, split bf16, 4 row-tiles x 2 k-slices
    bf16x8 xh[4][2], xl[4][2];
#pragma unroll
    for (int rt = 0; rt < 4; ++rt) {
        const float* xrow = x + (((size_t)(row0 + (rt << 4) + sub)) << 6) + (grp << 3);
#pragma unroll
        for (int s = 0; s < 2; ++s) {
            float4 f0 = *(const float4*)(xrow + (s << 5));
            float4 f1 = *(const float4*)(xrow + (s << 5) + 4);
            CVT8(f0, f1, xh[rt][s], xl[rt][s]);
        }
    }

    float m1[4], m2[4];
    int bi[4];
#pragma unroll
    for (int rt = 0; rt < 4; ++rt) { m1[rt] = -3e38f; m2[rt] = -3e38f; bi[rt] = 0; }

    bf16x8 a0, a1, a2, a3;  // eh slice0/1, el slice0/1
    f32x4 cb;
    LOADA(a0, a1, a2, a3, cb, 0);
    for (int tb = 0; tb < Kc; tb += 16) {
        bf16x8 n0, n1, n2, n3;
        f32x4 nb;
        int tn = tb + 16 < Kc ? tb + 16 : 0;
        LOADA(n0, n1, n2, n3, nb, tn);

        f32x4 acc[4];
#pragma unroll
        for (int rt = 0; rt < 4; ++rt) acc[rt] = cb;
#pragma unroll
        for (int rt = 0; rt < 4; ++rt)
            acc[rt] = __builtin_amdgcn_mfma_f32_16x16x32_bf16(a0, xh[rt][0], acc[rt], 0, 0, 0);
#pragma unroll
        for (int rt = 0; rt < 4; ++rt)
            acc[rt] = __builtin_amdgcn_mfma_f32_16x16x32_bf16(a2, xh[rt][0], acc[rt], 0, 0, 0);
#pragma unroll
        for (int rt = 0; rt < 4; ++rt)
            acc[rt] = __builtin_amdgcn_mfma_f32_16x16x32_bf16(a0, xl[rt][0], acc[rt], 0, 0, 0);
#pragma unroll
        for (int rt = 0; rt < 4; ++rt)
            acc[rt] = __builtin_amdgcn_mfma_f32_16x16x32_bf16(a1, xh[rt][1], acc[rt], 0, 0, 0);
#pragma unroll
        for (int rt = 0; rt < 4; ++rt)
            acc[rt] = __builtin_amdgcn_mfma_f32_16x16x32_bf16(a3, xh[rt][1], acc[rt], 0, 0, 0);
#pragma unroll
        for (int rt = 0; rt < 4; ++rt)
            acc[rt] = __builtin_amdgcn_mfma_f32_16x16x32_bf16(a1, xl[rt][1], acc[rt], 0, 0, 0);

        // top-2 argmax update; per-lane codes ascend -> np first-min
#pragma unroll
        for (int rt = 0; rt < 4; ++rt) {
#pragma unroll
            for (int j = 0; j < 4; ++j) {
                float a = acc[rt][j];
                int c = tb + (grp << 2) + j;
                float old = m1[rt];
                bool t = a > old;
                m1[rt] = t ? a : old;
                m2[rt] = fmaxf(fminf(a, old), m2[rt]);
                bi[rt] = t ? c : bi[rt];
            }
        }
        a0 = n0; a1 = n1; a2 = n2; a3 = n3; cb = nb;
    }

    // merge the 4 code-groups (lanes sub, sub+16, sub+32, sub+48)
#pragma unroll
    for (int rt = 0; rt < 4; ++rt) {
#pragma unroll
        for (int off = 16; off <= 32; off <<= 1) {
            float om1 = __shfl_xor(m1[rt], off);
            float om2 = __shfl_xor(m2[rt], off);
            int obi = __shfl_xor(bi[rt], off);
            bool take = (om1 > m1[rt]) || (om1 == m1[rt] && obi < bi[rt]);
            m2[rt] = fmaxf(fminf(om1, m1[rt]), fmaxf(om2, m2[rt]));
            m1[rt] = take ? om1 : m1[rt];
            bi[rt] = take ? obi : bi[rt];
        }
    }

    // decide + scalar outputs (lanes 0-15 own rows sub + 16*rt)
    int dec[4];
#pragma unroll
    for (int rt = 0; rt < 4; ++rt) dec[rt] = bi[rt];
    if (lane < 16) {
#pragma unroll
        for (int rt = 0; rt < 4; ++rt) {
            int row = row0 + (rt << 4) + lane;
            bool amb = 2.0f * (m1[rt] - m2[rt]) < MARGIN;
            if (amb) {
                unsigned pos = atomicAdd(nunc, 1u);
                if (pos < cap) {
                    list[pos] = (unsigned)row;
                    dec[rt] = -1;
                } else {
                    dec[rt] = np_exact_argmin(x + (size_t)row * D, emb, eenp, Kc);
                }
            }
            if (dec[rt] >= 0) {
                outidx[row] = (float)dec[rt];
                atomicAdd(counts + dec[rt], 1u);
            }
        }
    }

    // quantized + loss: pass p covers rows 16p..16p+15; 4 lanes per row
    double lpart = 0.0;
#pragma unroll
    for (int p = 0; p < 4; ++p) {
        int dp = __shfl(dec[p], lane >> 2);
        if (dp >= 0) {
            int row = row0 + (p << 4) + (lane >> 2);
            int qo = (lane & 3) << 4;
            const float4* ep = (const float4*)(emb + (size_t)dp * D + qo);
            const float4* xp = (const float4*)(x + (size_t)row * D + qo);
            float4* qp = (float4*)(outq + (size_t)row * D + qo);
#pragma unroll
            for (int j = 0; j < 4; ++j) {
                float4 ev = ep[j], xv = xp[j];
                qp[j] = ev;
                double d0 = (double)ev.x - (double)xv.x;
                double d1 = (double)ev.y - (double)xv.y;
                double d2 = (double)ev.z - (double)xv.z;
                double d3 = (double)ev.w - (double)xv.w;
                lpart += d0 * d0 + d1 * d1 + d2 * d2 + d3 * d3;
            }
        }
    }
#pragma unroll
    for (int off = 32; off; off >>= 1) lpart += __shfl_down(lpart, off);
    if (lane == 0) atomicAdd(loss, lpart);
}

// wave-per-row exact numpy-f32 argmin for ambiguous rows
__global__ __launch_bounds__(64) void vq_fallback(
    const float* __restrict__ x, const float* __restrict__ emb,
    const float* __restrict__ eenp, int N, int K,
    float* __restrict__ outq, float* __restrict__ outidx,
    unsigned* __restrict__ counts, double* __restrict__ loss,
    const unsigned* __restrict__ nunc, const unsigned* __restrict__ list,
    unsigned cap) {
    unsigned n = *nunc;
    if (n > cap) n = cap;
    int lane = threadIdx.x;
    const int KP = K / 64;  // 16
    __shared__ float sx[D];
    for (unsigned i = blockIdx.x; i < n; i += gridDim.x) {
        int r = (int)list[i];
        sx[lane] = x[(size_t)r * D + lane];
        __syncthreads();
        float xx = np_pairwise_sumsq64(sx);  // broadcast LDS reads, np-exact
        float bm = 1e30f;
        int bi = 0;
#pragma unroll 4
        for (int kk = 0; kk < KP; ++kk) {
            int k = lane * KP + kk;  // ascending within lane
            const float* e = emb + (size_t)k * D;
            float dot = 0.f;
#pragma unroll 8
            for (int d = 0; d < D; ++d) dot = __fmaf_rn(sx[d], e[d], dot);
            float dist = __fsub_rn(__fadd_rn(xx, eenp[k]), __fmul_rn(2.0f, dot));
            if (dist < bm) { bm = dist; bi = k; }
        }
#pragma unroll
        for (int off = 1; off < 64; off <<= 1) {
            float ov = __shfl_xor(bm, off);
            int oi = __shfl_xor(bi, off);
            if (ov < bm || (ov == bm && oi < bi)) { bm = ov; bi = oi; }
        }
        float ev = emb[(size_t)bi * D + lane];
        float xv = sx[lane];
        outq[(size_t)r * D + lane] = ev;
        double df = (double)ev - (double)xv;
        double lp = df * df;
#pragma unroll
        for (int off = 32; off; off >>= 1) lp += __shfl_down(lp, off);
        if (lane == 0) {
            outidx[r] = (float)bi;
            atomicAdd(counts + bi, 1u);
            atomicAdd(loss, lp);
        }
        __syncthreads();
    }
}

__global__ __launch_bounds__(256) void vq_final(
    const unsigned* __restrict__ counts, const double* __restrict__ loss,
    int N, int K, float* __restrict__ out_loss, float* __restrict__ out_perp) {
    double part = 0.0;
    for (int k = threadIdx.x; k < K; k += 256) {
        double p = (double)counts[k] / (double)N;
        part += p * log(p + 1e-10);
    }
#pragma unroll
    for (int off = 32; off; off >>= 1) part += __shfl_down(part, off);
    __shared__ double ls[4];
    if ((threadIdx.x & 63) == 0) ls[threadIdx.x >> 6] = part;
    __syncthreads();
    if (threadIdx.x == 0) {
        double s = ls[0] + ls[1] + ls[2] + ls[3];
        *out_perp = (float)exp(-s);
        double diff2 = *loss / ((double)N * (double)D);
        *out_loss = (float)(1.25 * diff2);
    }
}

extern "C" void kernel_launch(void* const* d_in, const int* in_sizes, int n_in,
                              void* d_out, int out_size, void* d_ws, size_t ws_size,
                              hipStream_t stream) {
    const float* x = (const float*)d_in[0];
    const float* emb = (const float*)d_in[1];
    int N = in_sizes[0] / D;
    int K = in_sizes[1] / D;

    float* outq = (float*)d_out;
    float* out_loss = outq + (size_t)N * D;
    float* outidx = out_loss + 1;
    float* out_perp = outidx + N;

    char* ws = (char*)d_ws;
    unsigned* counts = (unsigned*)ws;                          // K*4 = 4096
    unsigned* nunc = (unsigned*)(ws + (size_t)K * 4);          // 4 (+4 pad)
    double* loss = (double*)(ws + (size_t)K * 4 + 8);          // 8
    float* neh = (float*)(ws + (size_t)K * 4 + 16);            // K*4
    float* eenp = (float*)(ws + (size_t)K * 8 + 16);           // K*4
    unsigned short* eh = (unsigned short*)(ws + (size_t)K * 12 + 16);          // K*D*2
    unsigned short* el = (unsigned short*)(ws + (size_t)K * 12 + 16 + (size_t)K * D * 2);
    size_t head = (size_t)K * 12 + 16 + (size_t)K * D * 4;
    unsigned* list = (unsigned*)(ws + head);
    unsigned cap = 0;
    if (ws_size > head + 4) cap = (unsigned)((ws_size - head) / 4);
    if (cap > (unsigned)N) cap = (unsigned)N;

    hipMemsetAsync(d_ws, 0, (size_t)K * 4 + 16, stream);  // counts+nunc+loss

    vq_prep<<<(K + 255) / 256, 256, 0, stream>>>(emb, K, eenp, neh, eh, el);
    vq_screen<<<N / 256, 256, 0, stream>>>(x, emb, eh, el, neh, eenp, N, K,
                                           outq, outidx, counts, loss,
                                           nunc, list, cap);
    vq_fallback<<<2048, 64, 0, stream>>>(x, emb, eenp, N, K, outq, outidx,
                                         counts, loss, nunc, list, cap);
    vq_final<<<1, 256, 0, stream>>>(counts, loss, N, K, out_loss, out_perp);
}